// Round 4
// baseline (1268.309 us; speedup 1.0000x reference)
//
#include <hip/hip_runtime.h>
#include <math.h>

typedef float v2f __attribute__((ext_vector_type(2)));

#define LN2_INV 1.4426950408889634f

__device__ __forceinline__ float fexp2(float x) {
#if __has_builtin(__builtin_amdgcn_exp2f)
    return __builtin_amdgcn_exp2f(x);
#else
    return exp2f(x);
#endif
}

__device__ __forceinline__ int rdlane_i(int v, int k) {
    return __builtin_amdgcn_readlane(v, k);
}

// packed f32 math (gfx90a+ VOP3P; fp32 peak 157TF = 2x scalar => exists on gfx950)
__device__ __forceinline__ v2f pk_fma(v2f a, v2f b, v2f c) {
    asm("v_pk_fma_f32 %0, %1, %2, %0" : "+v"(c) : "v"(a), "v"(b));
    return c;
}
__device__ __forceinline__ v2f pk_add(v2f a, v2f b) {
    v2f d;
    asm("v_pk_add_f32 %0, %1, %2" : "=v"(d) : "v"(a), "v"(b));
    return d;
}
__device__ __forceinline__ v2f pk_mul(v2f a, v2f b) {
    v2f d;
    asm("v_pk_mul_f32 %0, %1, %2" : "=v"(d) : "v"(a), "v"(b));
    return d;
}

__device__ __forceinline__ v2f max2(v2f a, float b) {
    v2f r; r.x = fmaxf(a.x, b); r.y = fmaxf(a.y, b); return r;
}
__device__ __forceinline__ v2f min2(v2f a, float b) {
    v2f r; r.x = fminf(a.x, b); r.y = fminf(a.y, b); return r;
}

// v += dpp_shifted(v) within 16-lane rows; shifted-in lanes contribute 0.
#define DPP_ROW_ADD(V, CTRL) \
    V += __int_as_float(__builtin_amdgcn_update_dpp(0, __float_as_int(V), CTRL, 0xf, 0xf, true));

// ---------------------------------------------------------------------------
// k_h0: h0 = relu(x @ f_W + f_b), x [N,128], f_W [128,64]. 8 nodes/block.
// ---------------------------------------------------------------------------
__global__ __launch_bounds__(256) void k_h0(const float* __restrict__ x,
                                            const float* __restrict__ fW,
                                            const float* __restrict__ fb,
                                            float* __restrict__ h0) {
    __shared__ __align__(16) float xs[8 * 128];
    int t = threadIdx.x;
    int base = blockIdx.x * 8;
#pragma unroll
    for (int r = 0; r < 4; ++r) { int j = r * 256 + t; xs[j] = x[base * 128 + j]; }
    __syncthreads();
    int c = t & 63, half = t >> 6;
    float acc0 = fb[c], acc1 = fb[c];
    int m0 = half, m1 = half + 4;
#pragma unroll 8
    for (int k0 = 0; k0 < 128; k0 += 4) {
        float4 a = *(const float4*)&xs[m0 * 128 + k0];
        float4 b = *(const float4*)&xs[m1 * 128 + k0];
        float w0 = fW[(k0 + 0) * 64 + c], w1 = fW[(k0 + 1) * 64 + c];
        float w2 = fW[(k0 + 2) * 64 + c], w3 = fW[(k0 + 3) * 64 + c];
        acc0 = fmaf(a.x, w0, fmaf(a.y, w1, fmaf(a.z, w2, fmaf(a.w, w3, acc0))));
        acc1 = fmaf(b.x, w0, fmaf(b.y, w1, fmaf(b.z, w2, fmaf(b.w, w3, acc1))));
    }
    h0[(base + m0) * 64 + c] = fmaxf(acc0, 0.f);
    h0[(base + m1) * 64 + c] = fmaxf(acc1, 0.f);
}

// ---------------------------------------------------------------------------
// k_xlxr: xl = h@Wl + bl, xr = h@Wr + br, natural [N][256] layout (h*64+d).
// ---------------------------------------------------------------------------
__global__ __launch_bounds__(256) void k_xlxr(const float* __restrict__ h,
                                              const float* __restrict__ Wl,
                                              const float* __restrict__ Wr,
                                              const float* __restrict__ bl,
                                              const float* __restrict__ br,
                                              float* __restrict__ xl,
                                              float* __restrict__ xr) {
    __shared__ __align__(16) float hs[16 * 64];
    int t = threadIdx.x;
    int base = blockIdx.x * 16;
#pragma unroll
    for (int r = 0; r < 4; ++r) hs[r * 256 + t] = h[base * 64 + r * 256 + t];
    __syncthreads();
    float bL = bl[t], bR = br[t];
    float accl[16], accr[16];
#pragma unroll
    for (int m = 0; m < 16; ++m) { accl[m] = bL; accr[m] = bR; }
#pragma unroll 4
    for (int k0 = 0; k0 < 64; k0 += 4) {
        float wl[4], wr[4];
#pragma unroll
        for (int q = 0; q < 4; ++q) {
            wl[q] = Wl[(k0 + q) * 256 + t];
            wr[q] = Wr[(k0 + q) * 256 + t];
        }
#pragma unroll
        for (int m = 0; m < 16; ++m) {
            float4 hv = *(const float4*)&hs[m * 64 + k0];
            accl[m] = fmaf(hv.x, wl[0], fmaf(hv.y, wl[1], fmaf(hv.z, wl[2], fmaf(hv.w, wl[3], accl[m]))));
            accr[m] = fmaf(hv.x, wr[0], fmaf(hv.y, wr[1], fmaf(hv.z, wr[2], fmaf(hv.w, wr[3], accr[m]))));
        }
    }
#pragma unroll
    for (int m = 0; m < 16; ++m) {
        xl[(base + m) * 256 + t] = accl[m];
        xr[(base + m) * 256 + t] = accr[m];
    }
}

// ---------------------------------------------------------------------------
// CSR build. rec record (stride 24 ints): [0..19] = relu edge-MLP s_k,
// [20] = src node, [21..23] pad. 4 zeroed pad records past E let the edge
// loop prefetch unclamped (pad src=0 -> valid gather, values discarded).
// ---------------------------------------------------------------------------
__global__ void k_zero(int* __restrict__ deg, int* __restrict__ counter,
                       int* __restrict__ rec, int Nn, int Ee) {
    int i = blockIdx.x * 256 + threadIdx.x;
    if (i < Nn) deg[i] = 0;
    if (i == 0) *counter = 0;
    if (blockIdx.x == 0 && threadIdx.x < 96) rec[(size_t)Ee * 24 + threadIdx.x] = 0;
}

__global__ void k_count(const int* __restrict__ dstArr, int* __restrict__ deg, int Ee) {
    int e = blockIdx.x * 256 + threadIdx.x;
    if (e < Ee) atomicAdd(&deg[dstArr[e]], 1);
}

__global__ void k_alloc(const int* __restrict__ deg, int* __restrict__ counter,
                        int* __restrict__ start, int* __restrict__ cursor, int Nn) {
    int n = blockIdx.x * 256 + threadIdx.x;
    if (n < Nn) {
        int d = deg[n];
        int b = atomicAdd(counter, d);
        start[n] = b;
        cursor[n] = b;
    }
}

__global__ void k_fill(const int* __restrict__ dstArr, const int* __restrict__ srcArr,
                       const float* __restrict__ eattr, const float* __restrict__ feW,
                       const float* __restrict__ feb, int* __restrict__ cursor,
                       int* __restrict__ rec, int Ee) {
    int e = blockIdx.x * 256 + threadIdx.x;
    if (e >= Ee) return;
    float a0 = eattr[2 * e], a1 = eattr[2 * e + 1];
    int p = atomicAdd(&cursor[dstArr[e]], 1);
    float* r = (float*)(rec + (size_t)p * 24);
    float s[20];
#pragma unroll
    for (int k = 0; k < 20; ++k)
        s[k] = fmaxf(fmaf(a0, feW[k], fmaf(a1, feW[20 + k], feb[k])), 0.f);
#pragma unroll
    for (int j = 0; j < 5; ++j)
        ((float4*)r)[j] = make_float4(s[4 * j], s[4 * j + 1], s[4 * j + 2], s[4 * j + 3]);
    ((int*)r)[20] = srcArr[e];
}

// ---------------------------------------------------------------------------
// k_edge: one wave per dst node (4 nodes / 256-thread block). Lane = h*16+g,
// holds dims 4g..4g+3 of head h. Per edge:
//  - record staged into a per-wave LDS slot as DUPLICATED pairs {s_k,s_k}
//    (one ds_write_b64/lane); consumed as 20 uniform-address ds_read_b64
//    broadcasts feeding v_pk_fma_f32 directly: no readlanes, ee = 40 pk_fma.
//  - A/B unroll-2 software pipeline: raw records 2 ahead (registers), LDS
//    slots 1 edge ahead, xl gathers 1 full A/B iteration ahead. Pad records
//    make all prefetches unconditional (no clamps).
// ---------------------------------------------------------------------------
#define COMPUTE_EDGE(Sp, XL) do {                                            \
    v2f xl01 = {XL.x, XL.y}, xl23 = {XL.z, XL.w};                            \
    v2f sa = *(const v2f*)&Sp[0];                                            \
    v2f ea01 = pk_mul(sa, we01[0]);  v2f ea23 = pk_mul(sa, we23[0]);         \
    v2f sb = *(const v2f*)&Sp[2];                                            \
    v2f eb01 = pk_mul(sb, we01[1]);  v2f eb23 = pk_mul(sb, we23[1]);         \
    _Pragma("unroll")                                                        \
    for (int k = 2; k < 20; k += 2) {                                        \
        v2f ka = *(const v2f*)&Sp[2 * k];                                    \
        v2f kb = *(const v2f*)&Sp[2 * k + 2];                                \
        ea01 = pk_fma(ka, we01[k], ea01);                                    \
        ea23 = pk_fma(ka, we23[k], ea23);                                    \
        eb01 = pk_fma(kb, we01[k + 1], eb01);                                \
        eb23 = pk_fma(kb, we23[k + 1], eb23);                                \
    }                                                                        \
    v2f v01 = pk_add(pk_add(xl01, xr01), pk_add(ea01, eb01));                \
    v2f v23 = pk_add(pk_add(xl23, xr23), pk_add(ea23, eb23));                \
    v2f p01 = pk_fma(at201, min2(v01, 0.f), pk_mul(att01, max2(v01, 0.f))); \
    v2f p23 = pk_fma(at223, min2(v23, 0.f), pk_mul(att23, max2(v23, 0.f))); \
    v2f pr = pk_add(p01, p23);                                               \
    float ps = pr.x + pr.y;                                                  \
    DPP_ROW_ADD(ps, 0x111)                                                   \
    DPP_ROW_ADD(ps, 0x112)                                                   \
    DPP_ROW_ADD(ps, 0x114)                                                   \
    DPP_ROW_ADD(ps, 0x118)                                                   \
    float sc = __int_as_float(                                               \
        __builtin_amdgcn_ds_bpermute(bperm, __float_as_int(ps)));            \
    float w_ = fexp2(sc);                                                    \
    l += w_;                                                                 \
    v2f w2 = {w_, w_};                                                       \
    acc01 = pk_fma(w2, xl01, acc01);                                         \
    acc23 = pk_fma(w2, xl23, acc23);                                         \
} while (0)

#define STAGE(Sp, RV) do {                                                   \
    float _f = __int_as_float(RV);                                           \
    v2f _p = {_f, _f};                                                       \
    *(v2f*)&Sp[2 * lane] = _p;                                               \
} while (0)

__global__ __launch_bounds__(256, 3) void k_edge(
    const float4* __restrict__ xl4p, const float4* __restrict__ xr4p,
    const float* __restrict__ att, const float4* __restrict__ We4,
    const int* __restrict__ rec, const int* __restrict__ start,
    const int* __restrict__ deg, const float* __restrict__ bias,
    float* __restrict__ hout, int Nn) {
    const int lane = threadIdx.x & 63;
    const int wv = threadIdx.x >> 6;
    const int n = (int)((blockIdx.x * 256u + threadIdx.x) >> 6);
    if (n >= Nn) return;
    __shared__ __align__(16) float sbuf[4][2][128];  // 4 waves x 2 slots x 512B

    const int dn = __builtin_amdgcn_readfirstlane(deg[n]);
    float4 bias4 = ((const float4*)bias)[lane & 15];
    if (dn == 0) {
        if (lane < 16) {
            float4 o = make_float4(fmaxf(bias4.x, 0.f), fmaxf(bias4.y, 0.f),
                                   fmaxf(bias4.z, 0.f), fmaxf(bias4.w, 0.f));
            ((float4*)hout)[(size_t)n * 16 + lane] = o;
        }
        return;
    }
    const int s0 = __builtin_amdgcn_readfirstlane(start[n]);
    const int* rb = rec + (size_t)s0 * 24 + (lane & 31);

    // wave-invariant operands
    float4 attv = ((const float4*)att)[lane];
    v2f att01 = {attv.x * LN2_INV, attv.y * LN2_INV};
    v2f att23 = {attv.z * LN2_INV, attv.w * LN2_INV};
    v2f at201 = 0.2f * att01, at223 = 0.2f * att23;
    float4 xrv = xr4p[(size_t)n * 64 + lane];
    v2f xr01 = {xrv.x, xrv.y}, xr23 = {xrv.z, xrv.w};
    v2f we01[20], we23[20];
#pragma unroll
    for (int k = 0; k < 20; ++k) {
        float4 w = We4[k * 64 + lane];
        we01[k].x = w.x; we01[k].y = w.y;
        we23[k].x = w.z; we23[k].y = w.w;
    }
    const int bperm = ((lane & 48) | 15) << 2;
    float* sA = &sbuf[wv][0][0];
    float* sB = &sbuf[wv][1][0];

    v2f acc01 = {0.f, 0.f}, acc23 = {0.f, 0.f};
    float l = 0.f;

    // prologue: raw records 0..3; stage 0,1 into LDS; gathers for 0,1.
    int rvA = rb[0];
    int rvB = rb[24];
    int rvA2 = rb[48];
    int rvB2 = rb[72];
    STAGE(sA, rvA);
    STAGE(sB, rvB);
    int srcA = rdlane_i(rvA, 20);
    int srcB = rdlane_i(rvB, 20);
    float4 xlA = xl4p[(unsigned)(srcA * 64 + lane)];
    float4 xlB = xl4p[(unsigned)(srcB * 64 + lane)];

    const int nfull = dn >> 1;
    for (int t = 0; t < nfull; ++t) {
        // phase A: edge 2t (reads sA/xlA), then restage A for edge 2t+2
        COMPUTE_EDGE(sA, xlA);
        STAGE(sA, rvA2);
        {
            int srcN = rdlane_i(rvA2, 20);
            xlA = xl4p[(unsigned)(srcN * 64 + lane)];
            rvA2 = rb[(2 * t + 4) * 24];
        }
        // phase B: edge 2t+1
        COMPUTE_EDGE(sB, xlB);
        STAGE(sB, rvB2);
        {
            int srcN = rdlane_i(rvB2, 20);
            xlB = xl4p[(unsigned)(srcN * 64 + lane)];
            rvB2 = rb[(2 * t + 5) * 24];
        }
    }
    if (dn & 1) COMPUTE_EDGE(sA, xlA);

    // epilogue: res = relu(bias + 0.25 * sum_h acc_h / l_h)
    float inv = 0.25f / l;
    float4 r = make_float4(acc01.x * inv, acc01.y * inv, acc23.x * inv, acc23.y * inv);
    r.x += __shfl_xor(r.x, 16, 64); r.x += __shfl_xor(r.x, 32, 64);
    r.y += __shfl_xor(r.y, 16, 64); r.y += __shfl_xor(r.y, 32, 64);
    r.z += __shfl_xor(r.z, 16, 64); r.z += __shfl_xor(r.z, 32, 64);
    r.w += __shfl_xor(r.w, 16, 64); r.w += __shfl_xor(r.w, 32, 64);
    if (lane < 16) {
        float4 o = make_float4(fmaxf(r.x + bias4.x, 0.f), fmaxf(r.y + bias4.y, 0.f),
                               fmaxf(r.z + bias4.z, 0.f), fmaxf(r.w + bias4.w, 0.f));
        ((float4*)hout)[(size_t)n * 16 + lane] = o;
    }
}

// ---------------------------------------------------------------------------
extern "C" void kernel_launch(void* const* d_in, const int* in_sizes, int n_in,
                              void* d_out, int out_size, void* d_ws, size_t ws_size,
                              hipStream_t stream) {
    const float* x     = (const float*)d_in[0];
    const float* eattr = (const float*)d_in[1];
    const int*   eidx  = (const int*)d_in[2];
    const float* fW    = (const float*)d_in[3];
    const float* fb    = (const float*)d_in[4];
    const float* feW   = (const float*)d_in[5];
    const float* feb   = (const float*)d_in[6];
    const float* Wl    = (const float*)d_in[7];
    const float* bl    = (const float*)d_in[8];
    const float* Wr    = (const float*)d_in[9];
    const float* br    = (const float*)d_in[10];
    const float* We    = (const float*)d_in[11];
    const float* att   = (const float*)d_in[12];
    const float* bias  = (const float*)d_in[13];
    float* out = (float*)d_out;

    const int N = in_sizes[0] / 128;   // 50000
    const int E = in_sizes[1] / 2;     // 800000
    const int* srcArr = eidx;
    const int* dstArr = eidx + E;

    char* p = (char*)d_ws;
    auto alloc = [&](size_t bytes) -> char* {
        char* r = p;
        p += (bytes + 255) & ~(size_t)255;
        return r;
    };
    float* hA   = (float*)alloc((size_t)N * 64 * 4);
    float* hB   = (float*)alloc((size_t)N * 64 * 4);
    float* xl   = (float*)alloc((size_t)N * 256 * 4);
    float* xr   = (float*)alloc((size_t)N * 256 * 4);
    int* deg    = (int*)alloc((size_t)N * 4);
    int* start  = (int*)alloc((size_t)N * 4);
    int* cursor = (int*)alloc((size_t)N * 4);
    int* counter = (int*)alloc(256);
    int* rec    = (int*)alloc((size_t)(E + 4) * 24 * 4);

    k_h0<<<N / 8, 256, 0, stream>>>(x, fW, fb, hA);
    k_zero<<<(N + 255) / 256, 256, 0, stream>>>(deg, counter, rec, N, E);
    k_count<<<(E + 255) / 256, 256, 0, stream>>>(dstArr, deg, E);
    k_alloc<<<(N + 255) / 256, 256, 0, stream>>>(deg, counter, start, cursor, N);
    k_fill<<<(E + 255) / 256, 256, 0, stream>>>(dstArr, srcArr, eattr, feW, feb,
                                                cursor, rec, E);

    const float* hin = hA;
    for (int layer = 0; layer < 3; ++layer) {
        float* hout = (layer == 2) ? out : ((layer == 0) ? hB : hA);
        k_xlxr<<<N / 16, 256, 0, stream>>>(hin, Wl, Wr, bl, br, xl, xr);
        k_edge<<<(N * 64) / 256, 256, 0, stream>>>(
            (const float4*)xl, (const float4*)xr, att, (const float4*)We,
            rec, start, deg, bias, hout, N);
        hin = hout;
    }
}

// Round 5
// 967.222 us; speedup vs baseline: 1.3113x; 1.3113x over previous
//
#include <hip/hip_runtime.h>
#include <math.h>

typedef float v2f __attribute__((ext_vector_type(2)));

#define LN2_INV 1.4426950408889634f

__device__ __forceinline__ float fexp2(float x) {
#if __has_builtin(__builtin_amdgcn_exp2f)
    return __builtin_amdgcn_exp2f(x);
#else
    return exp2f(x);
#endif
}

// packed f32 VOP3P (proven to assemble+validate on gfx950 in round 4)
__device__ __forceinline__ v2f pk_fma(v2f a, v2f b, v2f c) {
    asm("v_pk_fma_f32 %0, %1, %2, %0" : "+v"(c) : "v"(a), "v"(b));
    return c;
}
// variants with the broadcast pair in SGPRs (VOP3P permits one scalar source)
__device__ __forceinline__ v2f pk_fma_s(v2f a_s, v2f b, v2f c) {
    asm("v_pk_fma_f32 %0, %1, %2, %0" : "+v"(c) : "s"(a_s), "v"(b));
    return c;
}
__device__ __forceinline__ v2f pk_mul_s(v2f a_s, v2f b) {
    v2f d;
    asm("v_pk_mul_f32 %0, %1, %2" : "=v"(d) : "s"(a_s), "v"(b));
    return d;
}

// v += dpp_shifted(v) within 16-lane rows; shifted-in lanes contribute 0.
#define DPP_ROW_ADD(V, CTRL) \
    V += __int_as_float(__builtin_amdgcn_update_dpp(0, __float_as_int(V), CTRL, 0xf, 0xf, true));

// ---------------------------------------------------------------------------
// k_h0: h0 = relu(x @ f_W + f_b), x [N,128], f_W [128,64]. 8 nodes/block.
// ---------------------------------------------------------------------------
__global__ __launch_bounds__(256) void k_h0(const float* __restrict__ x,
                                            const float* __restrict__ fW,
                                            const float* __restrict__ fb,
                                            float* __restrict__ h0) {
    __shared__ __align__(16) float xs[8 * 128];
    int t = threadIdx.x;
    int base = blockIdx.x * 8;
#pragma unroll
    for (int r = 0; r < 4; ++r) { int j = r * 256 + t; xs[j] = x[base * 128 + j]; }
    __syncthreads();
    int c = t & 63, half = t >> 6;
    float acc0 = fb[c], acc1 = fb[c];
    int m0 = half, m1 = half + 4;
#pragma unroll 8
    for (int k0 = 0; k0 < 128; k0 += 4) {
        float4 a = *(const float4*)&xs[m0 * 128 + k0];
        float4 b = *(const float4*)&xs[m1 * 128 + k0];
        float w0 = fW[(k0 + 0) * 64 + c], w1 = fW[(k0 + 1) * 64 + c];
        float w2 = fW[(k0 + 2) * 64 + c], w3 = fW[(k0 + 3) * 64 + c];
        acc0 = fmaf(a.x, w0, fmaf(a.y, w1, fmaf(a.z, w2, fmaf(a.w, w3, acc0))));
        acc1 = fmaf(b.x, w0, fmaf(b.y, w1, fmaf(b.z, w2, fmaf(b.w, w3, acc1))));
    }
    h0[(base + m0) * 64 + c] = fmaxf(acc0, 0.f);
    h0[(base + m1) * 64 + c] = fmaxf(acc1, 0.f);
}

// ---------------------------------------------------------------------------
// k_xlxr: xl = h@Wl + bl, xr = h@Wr + br, natural [N][256] layout (h*64+d).
// ---------------------------------------------------------------------------
__global__ __launch_bounds__(256) void k_xlxr(const float* __restrict__ h,
                                              const float* __restrict__ Wl,
                                              const float* __restrict__ Wr,
                                              const float* __restrict__ bl,
                                              const float* __restrict__ br,
                                              float* __restrict__ xl,
                                              float* __restrict__ xr) {
    __shared__ __align__(16) float hs[16 * 64];
    int t = threadIdx.x;
    int base = blockIdx.x * 16;
#pragma unroll
    for (int r = 0; r < 4; ++r) hs[r * 256 + t] = h[base * 64 + r * 256 + t];
    __syncthreads();
    float bL = bl[t], bR = br[t];
    float accl[16], accr[16];
#pragma unroll
    for (int m = 0; m < 16; ++m) { accl[m] = bL; accr[m] = bR; }
#pragma unroll 4
    for (int k0 = 0; k0 < 64; k0 += 4) {
        float wl[4], wr[4];
#pragma unroll
        for (int q = 0; q < 4; ++q) {
            wl[q] = Wl[(k0 + q) * 256 + t];
            wr[q] = Wr[(k0 + q) * 256 + t];
        }
#pragma unroll
        for (int m = 0; m < 16; ++m) {
            float4 hv = *(const float4*)&hs[m * 64 + k0];
            accl[m] = fmaf(hv.x, wl[0], fmaf(hv.y, wl[1], fmaf(hv.z, wl[2], fmaf(hv.w, wl[3], accl[m]))));
            accr[m] = fmaf(hv.x, wr[0], fmaf(hv.y, wr[1], fmaf(hv.z, wr[2], fmaf(hv.w, wr[3], accr[m]))));
        }
    }
#pragma unroll
    for (int m = 0; m < 16; ++m) {
        xl[(base + m) * 256 + t] = accl[m];
        xr[(base + m) * 256 + t] = accr[m];
    }
}

// ---------------------------------------------------------------------------
// CSR build. rec record (stride 24 ints): [0..19] = relu edge-MLP s_k,
// [20] = src node, [21..23] pad. 4 zeroed pad records past E let the edge
// loop prefetch unconditionally (pad src=0 -> valid gather, values unused).
// ---------------------------------------------------------------------------
__global__ void k_zero(int* __restrict__ deg, int* __restrict__ counter,
                       int* __restrict__ rec, int Nn, int Ee) {
    int i = blockIdx.x * 256 + threadIdx.x;
    if (i < Nn) deg[i] = 0;
    if (i == 0) *counter = 0;
    if (blockIdx.x == 0 && threadIdx.x < 96) rec[(size_t)Ee * 24 + threadIdx.x] = 0;
}

__global__ void k_count(const int* __restrict__ dstArr, int* __restrict__ deg, int Ee) {
    int e = blockIdx.x * 256 + threadIdx.x;
    if (e < Ee) atomicAdd(&deg[dstArr[e]], 1);
}

__global__ void k_alloc(const int* __restrict__ deg, int* __restrict__ counter,
                        int* __restrict__ start, int* __restrict__ cursor, int Nn) {
    int n = blockIdx.x * 256 + threadIdx.x;
    if (n < Nn) {
        int d = deg[n];
        int b = atomicAdd(counter, d);
        start[n] = b;
        cursor[n] = b;
    }
}

__global__ void k_fill(const int* __restrict__ dstArr, const int* __restrict__ srcArr,
                       const float* __restrict__ eattr, const float* __restrict__ feW,
                       const float* __restrict__ feb, int* __restrict__ cursor,
                       int* __restrict__ rec, int Ee) {
    int e = blockIdx.x * 256 + threadIdx.x;
    if (e >= Ee) return;
    float a0 = eattr[2 * e], a1 = eattr[2 * e + 1];
    int p = atomicAdd(&cursor[dstArr[e]], 1);
    float* r = (float*)(rec + (size_t)p * 24);
    float s[20];
#pragma unroll
    for (int k = 0; k < 20; ++k)
        s[k] = fmaxf(fmaf(a0, feW[k], fmaf(a1, feW[20 + k], feb[k])), 0.f);
#pragma unroll
    for (int j = 0; j < 5; ++j)
        ((float4*)r)[j] = make_float4(s[4 * j], s[4 * j + 1], s[4 * j + 2], s[4 * j + 3]);
    ((int*)r)[20] = srcArr[e];
}

// ---------------------------------------------------------------------------
// k_edge: one wave per dst node (4 nodes / 256-thread block). Lane = h*16+g,
// holds dims 4g..4g+3 of head h (natural h*64+d order).
//  - Edge records are read via wave-uniform SCALAR loads (base from
//    readfirstlane'd CSR start): s_load_dwordx16/x4 puts the 20 s_k in SGPRs.
//    No vector record load, no readlanes, no rotation movs.
//  - ee matvec: k-interleaved We layout (weI_d[p] = {We[2p][d],We[2p+1][d]})
//    consumed by v_pk_fma_f32 with the {s_2p,s_2p+1} broadcast pair as the
//    single scalar source -> 40 pk_fma + 4 folds instead of 80 scalar FMA.
//  - A/B unroll-2: record blocks 2 edges deep (SGPR), dedicated src scalar
//    chain 4 deep, xl gathers 2 edges ahead. Pad records -> no clamps.
// ---------------------------------------------------------------------------
#define LOAD_BLOCK(SK, E_) do {                                              \
    const float* _rp = rf + (size_t)(E_) * 24;                               \
    _Pragma("unroll")                                                        \
    for (int _k = 0; _k < 20; ++_k) SK[_k] = _rp[_k];                        \
} while (0)

#define COMPUTE_EDGE(SK, XL) do {                                            \
    v2f _sp0 = {SK[0], SK[1]};                                               \
    v2f _a0 = pk_mul_s(_sp0, weI0[0]);                                       \
    v2f _a1 = pk_mul_s(_sp0, weI1[0]);                                       \
    v2f _a2 = pk_mul_s(_sp0, weI2[0]);                                       \
    v2f _a3 = pk_mul_s(_sp0, weI3[0]);                                       \
    _Pragma("unroll")                                                        \
    for (int _p = 1; _p < 10; ++_p) {                                        \
        v2f _s = {SK[2 * _p], SK[2 * _p + 1]};                               \
        _a0 = pk_fma_s(_s, weI0[_p], _a0);                                   \
        _a1 = pk_fma_s(_s, weI1[_p], _a1);                                   \
        _a2 = pk_fma_s(_s, weI2[_p], _a2);                                   \
        _a3 = pk_fma_s(_s, weI3[_p], _a3);                                   \
    }                                                                        \
    float _v0 = (XL.x + xrv.x) + (_a0.x + _a0.y);                            \
    float _v1 = (XL.y + xrv.y) + (_a1.x + _a1.y);                            \
    float _v2 = (XL.z + xrv.z) + (_a2.x + _a2.y);                            \
    float _v3 = (XL.w + xrv.w) + (_a3.x + _a3.y);                            \
    float _m0 = fmaxf(_v0, 0.2f * _v0);                                      \
    float _m1 = fmaxf(_v1, 0.2f * _v1);                                      \
    float _m2 = fmaxf(_v2, 0.2f * _v2);                                      \
    float _m3 = fmaxf(_v3, 0.2f * _v3);                                      \
    float _ps = fmaf(at0, _m0, fmaf(at1, _m1, fmaf(at2, _m2, at3 * _m3)));   \
    DPP_ROW_ADD(_ps, 0x111)                                                  \
    DPP_ROW_ADD(_ps, 0x112)                                                  \
    DPP_ROW_ADD(_ps, 0x114)                                                  \
    DPP_ROW_ADD(_ps, 0x118)                                                  \
    float _sc = __int_as_float(                                              \
        __builtin_amdgcn_ds_bpermute(bperm, __float_as_int(_ps)));           \
    float _w = fexp2(_sc);                                                   \
    l += _w;                                                                 \
    v2f _w2 = {_w, _w};                                                      \
    v2f _xl01 = {XL.x, XL.y}, _xl23 = {XL.z, XL.w};                          \
    acc01 = pk_fma(_w2, _xl01, acc01);                                       \
    acc23 = pk_fma(_w2, _xl23, acc23);                                       \
} while (0)

__global__ __launch_bounds__(256, 3) void k_edge(
    const float4* __restrict__ xl4p, const float4* __restrict__ xr4p,
    const float* __restrict__ att, const float4* __restrict__ We4,
    const int* __restrict__ rec, const int* __restrict__ start,
    const int* __restrict__ deg, const float* __restrict__ bias,
    float* __restrict__ hout, int Nn) {
    const int lane = threadIdx.x & 63;
    const int n = (int)((blockIdx.x * 256u + threadIdx.x) >> 6);
    if (n >= Nn) return;

    const int dn = __builtin_amdgcn_readfirstlane(deg[n]);
    float4 bias4 = ((const float4*)bias)[lane & 15];
    if (dn == 0) {
        if (lane < 16) {
            float4 o = make_float4(fmaxf(bias4.x, 0.f), fmaxf(bias4.y, 0.f),
                                   fmaxf(bias4.z, 0.f), fmaxf(bias4.w, 0.f));
            ((float4*)hout)[(size_t)n * 16 + lane] = o;
        }
        return;
    }
    const int s0 = __builtin_amdgcn_readfirstlane(start[n]);
    const float* rf = (const float*)rec + (size_t)s0 * 24;  // uniform base
    const int* ri = rec + (size_t)s0 * 24;

    // wave-invariant operands
    float4 attv = ((const float4*)att)[lane];
    float at0 = attv.x * LN2_INV, at1 = attv.y * LN2_INV;
    float at2 = attv.z * LN2_INV, at3 = attv.w * LN2_INV;
    float4 xrv = xr4p[(size_t)n * 64 + lane];
    // We, k-interleaved per dim: weI_d[p] = {We[2p][d], We[2p+1][d]}
    v2f weI0[10], weI1[10], weI2[10], weI3[10];
#pragma unroll
    for (int p = 0; p < 10; ++p) {
        float4 w0 = We4[(2 * p) * 64 + lane];
        float4 w1 = We4[(2 * p + 1) * 64 + lane];
        weI0[p].x = w0.x; weI0[p].y = w1.x;
        weI1[p].x = w0.y; weI1[p].y = w1.y;
        weI2[p].x = w0.z; weI2[p].y = w1.z;
        weI3[p].x = w0.w; weI3[p].y = w1.w;
    }
    const int bperm = ((lane & 48) | 15) << 2;

    v2f acc01 = {0.f, 0.f}, acc23 = {0.f, 0.f};
    float l = 0.f;

    // prologue: record blocks 0,1 (SGPR); gathers for edges 0,1; srcs for 2,3
    float skA[20], skB[20];
    LOAD_BLOCK(skA, 0);
    LOAD_BLOCK(skB, 1);
    int sA0 = ri[20];
    int sB0 = ri[44];
    float4 xlA = xl4p[(size_t)(unsigned)sA0 * 64 + lane];
    float4 xlB = xl4p[(size_t)(unsigned)sB0 * 64 + lane];
    int srcA = ri[2 * 24 + 20];
    int srcB = ri[3 * 24 + 20];

    const int nfull = dn >> 1;
    for (int t = 0; t < nfull; ++t) {
        // phase A: edge 2t
        float4 xlA2 = xl4p[(size_t)(unsigned)srcA * 64 + lane];  // edge 2t+2
        srcA = ri[(size_t)(2 * t + 4) * 24 + 20];                // src 2t+4
        COMPUTE_EDGE(skA, xlA);
        LOAD_BLOCK(skA, 2 * t + 2);
        xlA = xlA2;
        // phase B: edge 2t+1
        float4 xlB2 = xl4p[(size_t)(unsigned)srcB * 64 + lane];  // edge 2t+3
        srcB = ri[(size_t)(2 * t + 5) * 24 + 20];                // src 2t+5
        COMPUTE_EDGE(skB, xlB);
        LOAD_BLOCK(skB, 2 * t + 3);
        xlB = xlB2;
    }
    if (dn & 1) COMPUTE_EDGE(skA, xlA);

    // epilogue: res = relu(bias + 0.25 * sum_h acc_h / l_h)
    float inv = 0.25f / l;
    float4 r = make_float4(acc01.x * inv, acc01.y * inv, acc23.x * inv, acc23.y * inv);
    r.x += __shfl_xor(r.x, 16, 64); r.x += __shfl_xor(r.x, 32, 64);
    r.y += __shfl_xor(r.y, 16, 64); r.y += __shfl_xor(r.y, 32, 64);
    r.z += __shfl_xor(r.z, 16, 64); r.z += __shfl_xor(r.z, 32, 64);
    r.w += __shfl_xor(r.w, 16, 64); r.w += __shfl_xor(r.w, 32, 64);
    if (lane < 16) {
        float4 o = make_float4(fmaxf(r.x + bias4.x, 0.f), fmaxf(r.y + bias4.y, 0.f),
                               fmaxf(r.z + bias4.z, 0.f), fmaxf(r.w + bias4.w, 0.f));
        ((float4*)hout)[(size_t)n * 16 + lane] = o;
    }
}

// ---------------------------------------------------------------------------
extern "C" void kernel_launch(void* const* d_in, const int* in_sizes, int n_in,
                              void* d_out, int out_size, void* d_ws, size_t ws_size,
                              hipStream_t stream) {
    const float* x     = (const float*)d_in[0];
    const float* eattr = (const float*)d_in[1];
    const int*   eidx  = (const int*)d_in[2];
    const float* fW    = (const float*)d_in[3];
    const float* fb    = (const float*)d_in[4];
    const float* feW   = (const float*)d_in[5];
    const float* feb   = (const float*)d_in[6];
    const float* Wl    = (const float*)d_in[7];
    const float* bl    = (const float*)d_in[8];
    const float* Wr    = (const float*)d_in[9];
    const float* br    = (const float*)d_in[10];
    const float* We    = (const float*)d_in[11];
    const float* att   = (const float*)d_in[12];
    const float* bias  = (const float*)d_in[13];
    float* out = (float*)d_out;

    const int N = in_sizes[0] / 128;   // 50000
    const int E = in_sizes[1] / 2;     // 800000
    const int* srcArr = eidx;
    const int* dstArr = eidx + E;

    char* p = (char*)d_ws;
    auto alloc = [&](size_t bytes) -> char* {
        char* r = p;
        p += (bytes + 255) & ~(size_t)255;
        return r;
    };
    float* hA   = (float*)alloc((size_t)N * 64 * 4);
    float* hB   = (float*)alloc((size_t)N * 64 * 4);
    float* xl   = (float*)alloc((size_t)N * 256 * 4);
    float* xr   = (float*)alloc((size_t)N * 256 * 4);
    int* deg    = (int*)alloc((size_t)N * 4);
    int* start  = (int*)alloc((size_t)N * 4);
    int* cursor = (int*)alloc((size_t)N * 4);
    int* counter = (int*)alloc(256);
    int* rec    = (int*)alloc((size_t)(E + 4) * 24 * 4);

    k_h0<<<N / 8, 256, 0, stream>>>(x, fW, fb, hA);
    k_zero<<<(N + 255) / 256, 256, 0, stream>>>(deg, counter, rec, N, E);
    k_count<<<(E + 255) / 256, 256, 0, stream>>>(dstArr, deg, E);
    k_alloc<<<(N + 255) / 256, 256, 0, stream>>>(deg, counter, start, cursor, N);
    k_fill<<<(E + 255) / 256, 256, 0, stream>>>(dstArr, srcArr, eattr, feW, feb,
                                                cursor, rec, E);

    const float* hin = hA;
    for (int layer = 0; layer < 3; ++layer) {
        float* hout = (layer == 2) ? out : ((layer == 0) ? hB : hA);
        k_xlxr<<<N / 16, 256, 0, stream>>>(hin, Wl, Wr, bl, br, xl, xr);
        k_edge<<<(N * 64) / 256, 256, 0, stream>>>(
            (const float4*)xl, (const float4*)xr, att, (const float4*)We,
            rec, start, deg, bias, hout, N);
        hin = hout;
    }
}

// Round 6
// 953.577 us; speedup vs baseline: 1.3301x; 1.0143x over previous
//
#include <hip/hip_runtime.h>
#include <math.h>

typedef float v2f __attribute__((ext_vector_type(2)));
typedef float v4f __attribute__((ext_vector_type(4)));

#define LN2_INV 1.4426950408889634f

__device__ __forceinline__ float fexp2(float x) {
#if __has_builtin(__builtin_amdgcn_exp2f)
    return __builtin_amdgcn_exp2f(x);
#else
    return exp2f(x);
#endif
}

// packed f32 VOP3P (proven to assemble+validate on gfx950, rounds 4-5)
__device__ __forceinline__ v2f pk_fma(v2f a, v2f b, v2f c) {
    asm("v_pk_fma_f32 %0, %1, %2, %0" : "+v"(c) : "v"(a), "v"(b));
    return c;
}
__device__ __forceinline__ v2f pk_fma_s(v2f a_s, v2f b, v2f c) {
    asm("v_pk_fma_f32 %0, %1, %2, %0" : "+v"(c) : "s"(a_s), "v"(b));
    return c;
}
__device__ __forceinline__ v2f pk_mul_s(v2f a_s, v2f b) {
    v2f d;
    asm("v_pk_mul_f32 %0, %1, %2" : "=v"(d) : "s"(a_s), "v"(b));
    return d;
}

// Pin a value in registers at this program point (prevents load sinking).
#define PIN_V(X) asm("" : "+v"(X))
#define PIN_S(X) asm("" : "+s"(X))

// v += dpp_shifted(v) within 16-lane rows; shifted-in lanes contribute 0.
#define DPP_ROW_ADD(V, CTRL) \
    V += __int_as_float(__builtin_amdgcn_update_dpp(0, __float_as_int(V), CTRL, 0xf, 0xf, true));

// ---------------------------------------------------------------------------
// k_h0: h0 = relu(x @ f_W + f_b), x [N,128], f_W [128,64]. 8 nodes/block.
// ---------------------------------------------------------------------------
__global__ __launch_bounds__(256) void k_h0(const float* __restrict__ x,
                                            const float* __restrict__ fW,
                                            const float* __restrict__ fb,
                                            float* __restrict__ h0) {
    __shared__ __align__(16) float xs[8 * 128];
    int t = threadIdx.x;
    int base = blockIdx.x * 8;
#pragma unroll
    for (int r = 0; r < 4; ++r) { int j = r * 256 + t; xs[j] = x[base * 128 + j]; }
    __syncthreads();
    int c = t & 63, half = t >> 6;
    float acc0 = fb[c], acc1 = fb[c];
    int m0 = half, m1 = half + 4;
#pragma unroll 8
    for (int k0 = 0; k0 < 128; k0 += 4) {
        float4 a = *(const float4*)&xs[m0 * 128 + k0];
        float4 b = *(const float4*)&xs[m1 * 128 + k0];
        float w0 = fW[(k0 + 0) * 64 + c], w1 = fW[(k0 + 1) * 64 + c];
        float w2 = fW[(k0 + 2) * 64 + c], w3 = fW[(k0 + 3) * 64 + c];
        acc0 = fmaf(a.x, w0, fmaf(a.y, w1, fmaf(a.z, w2, fmaf(a.w, w3, acc0))));
        acc1 = fmaf(b.x, w0, fmaf(b.y, w1, fmaf(b.z, w2, fmaf(b.w, w3, acc1))));
    }
    h0[(base + m0) * 64 + c] = fmaxf(acc0, 0.f);
    h0[(base + m1) * 64 + c] = fmaxf(acc1, 0.f);
}

// ---------------------------------------------------------------------------
// k_xlxr: xl = h@Wl + bl, xr = h@Wr + br, natural [N][256] layout (h*64+d).
// ---------------------------------------------------------------------------
__global__ __launch_bounds__(256) void k_xlxr(const float* __restrict__ h,
                                              const float* __restrict__ Wl,
                                              const float* __restrict__ Wr,
                                              const float* __restrict__ bl,
                                              const float* __restrict__ br,
                                              float* __restrict__ xl,
                                              float* __restrict__ xr) {
    __shared__ __align__(16) float hs[16 * 64];
    int t = threadIdx.x;
    int base = blockIdx.x * 16;
#pragma unroll
    for (int r = 0; r < 4; ++r) hs[r * 256 + t] = h[base * 64 + r * 256 + t];
    __syncthreads();
    float bL = bl[t], bR = br[t];
    float accl[16], accr[16];
#pragma unroll
    for (int m = 0; m < 16; ++m) { accl[m] = bL; accr[m] = bR; }
#pragma unroll 4
    for (int k0 = 0; k0 < 64; k0 += 4) {
        float wl[4], wr[4];
#pragma unroll
        for (int q = 0; q < 4; ++q) {
            wl[q] = Wl[(k0 + q) * 256 + t];
            wr[q] = Wr[(k0 + q) * 256 + t];
        }
#pragma unroll
        for (int m = 0; m < 16; ++m) {
            float4 hv = *(const float4*)&hs[m * 64 + k0];
            accl[m] = fmaf(hv.x, wl[0], fmaf(hv.y, wl[1], fmaf(hv.z, wl[2], fmaf(hv.w, wl[3], accl[m]))));
            accr[m] = fmaf(hv.x, wr[0], fmaf(hv.y, wr[1], fmaf(hv.z, wr[2], fmaf(hv.w, wr[3], accr[m]))));
        }
    }
#pragma unroll
    for (int m = 0; m < 16; ++m) {
        xl[(base + m) * 256 + t] = accl[m];
        xr[(base + m) * 256 + t] = accr[m];
    }
}

// ---------------------------------------------------------------------------
// CSR build. rec record (stride 20 ints = 80B): [0..19] = relu edge-MLP s_k.
// src node ids go to a separate dense sidx[] (sequential, prefetch-friendly).
// 8 zeroed pad records + pad sidx entries let the edge loop prefetch
// unconditionally (pad src=0 -> valid gather, values unused).
// ---------------------------------------------------------------------------
__global__ void k_zero(int* __restrict__ deg, int* __restrict__ counter,
                       int* __restrict__ rec, int* __restrict__ sidx,
                       int Nn, int Ee) {
    int i = blockIdx.x * 256 + threadIdx.x;
    if (i < Nn) deg[i] = 0;
    if (i == 0) *counter = 0;
    if (blockIdx.x == 0 && threadIdx.x < 160) rec[(size_t)Ee * 20 + threadIdx.x] = 0;
    if (blockIdx.x == 0 && threadIdx.x < 8) sidx[Ee + threadIdx.x] = 0;
}

__global__ void k_count(const int* __restrict__ dstArr, int* __restrict__ deg, int Ee) {
    int e = blockIdx.x * 256 + threadIdx.x;
    if (e < Ee) atomicAdd(&deg[dstArr[e]], 1);
}

__global__ void k_alloc(const int* __restrict__ deg, int* __restrict__ counter,
                        int* __restrict__ start, int* __restrict__ cursor, int Nn) {
    int n = blockIdx.x * 256 + threadIdx.x;
    if (n < Nn) {
        int d = deg[n];
        int b = atomicAdd(counter, d);
        start[n] = b;
        cursor[n] = b;
    }
}

__global__ void k_fill(const int* __restrict__ dstArr, const int* __restrict__ srcArr,
                       const float* __restrict__ eattr, const float* __restrict__ feW,
                       const float* __restrict__ feb, int* __restrict__ cursor,
                       int* __restrict__ rec, int* __restrict__ sidx, int Ee) {
    int e = blockIdx.x * 256 + threadIdx.x;
    if (e >= Ee) return;
    float a0 = eattr[2 * e], a1 = eattr[2 * e + 1];
    int p = atomicAdd(&cursor[dstArr[e]], 1);
    float* r = (float*)(rec + (size_t)p * 20);
    float s[20];
#pragma unroll
    for (int k = 0; k < 20; ++k)
        s[k] = fmaxf(fmaf(a0, feW[k], fmaf(a1, feW[20 + k], feb[k])), 0.f);
#pragma unroll
    for (int j = 0; j < 5; ++j)
        ((float4*)r)[j] = make_float4(s[4 * j], s[4 * j + 1], s[4 * j + 2], s[4 * j + 3]);
    sidx[p] = srcArr[e];
}

// ---------------------------------------------------------------------------
// k_edge: one wave per dst node (4 nodes / 256-thread block). Lane = h*16+g,
// holds dims 4g..4g+3 of head h (natural h*64+d order).
//  - Edge records via wave-uniform SCALAR loads (s_load) from readfirstlane'd
//    CSR base; s_k live in SGPRs feeding v_pk_fma_f32 (one scalar source).
//  - ee matvec: k-interleaved We layout, 40 pk_fma + folds (proven R5:
//    VALU busy 145->120 us/layer).
//  - Pipeline vs R5 (which stalled, VALUBusy 58%): xl chains 3-deep (gather
//    issued 2 A/B iterations = 4 edges before use, ~1200cyc cover), src ids
//    from sequential sidx[], and all prefetched values PINNED via empty asm
//    so the compiler cannot sink the loads to their use.
// ---------------------------------------------------------------------------
#define LOAD_BLOCK(SK, E_) do {                                              \
    const float* _rp = rf + (size_t)(E_) * 20;                               \
    _Pragma("unroll")                                                        \
    for (int _k = 0; _k < 20; ++_k) SK[_k] = _rp[_k];                        \
} while (0)

#define COMPUTE_EDGE(SK, XL) do {                                            \
    v2f _sp0 = {SK[0], SK[1]};                                               \
    v2f _a0 = pk_mul_s(_sp0, weI0[0]);                                       \
    v2f _a1 = pk_mul_s(_sp0, weI1[0]);                                       \
    v2f _a2 = pk_mul_s(_sp0, weI2[0]);                                       \
    v2f _a3 = pk_mul_s(_sp0, weI3[0]);                                       \
    _Pragma("unroll")                                                        \
    for (int _p = 1; _p < 10; ++_p) {                                        \
        v2f _s = {SK[2 * _p], SK[2 * _p + 1]};                               \
        _a0 = pk_fma_s(_s, weI0[_p], _a0);                                   \
        _a1 = pk_fma_s(_s, weI1[_p], _a1);                                   \
        _a2 = pk_fma_s(_s, weI2[_p], _a2);                                   \
        _a3 = pk_fma_s(_s, weI3[_p], _a3);                                   \
    }                                                                        \
    float _v0 = (XL.x + xrv.x) + (_a0.x + _a0.y);                            \
    float _v1 = (XL.y + xrv.y) + (_a1.x + _a1.y);                            \
    float _v2 = (XL.z + xrv.z) + (_a2.x + _a2.y);                            \
    float _v3 = (XL.w + xrv.w) + (_a3.x + _a3.y);                            \
    float _m0 = fmaxf(_v0, 0.2f * _v0);                                      \
    float _m1 = fmaxf(_v1, 0.2f * _v1);                                      \
    float _m2 = fmaxf(_v2, 0.2f * _v2);                                      \
    float _m3 = fmaxf(_v3, 0.2f * _v3);                                      \
    float _ps = fmaf(at0, _m0, fmaf(at1, _m1, fmaf(at2, _m2, at3 * _m3)));   \
    DPP_ROW_ADD(_ps, 0x111)                                                  \
    DPP_ROW_ADD(_ps, 0x112)                                                  \
    DPP_ROW_ADD(_ps, 0x114)                                                  \
    DPP_ROW_ADD(_ps, 0x118)                                                  \
    float _sc = __int_as_float(                                              \
        __builtin_amdgcn_ds_bpermute(bperm, __float_as_int(_ps)));           \
    float _w = fexp2(_sc);                                                   \
    l += _w;                                                                 \
    v2f _w2 = {_w, _w};                                                      \
    v2f _xl01 = {XL.x, XL.y}, _xl23 = {XL.z, XL.w};                          \
    acc01 = pk_fma(_w2, _xl01, acc01);                                       \
    acc23 = pk_fma(_w2, _xl23, acc23);                                       \
} while (0)

__global__ __launch_bounds__(256, 3) void k_edge(
    const v4f* __restrict__ xl4p, const v4f* __restrict__ xr4p,
    const float* __restrict__ att, const float4* __restrict__ We4,
    const int* __restrict__ rec, const int* __restrict__ sidx,
    const int* __restrict__ start, const int* __restrict__ deg,
    const float* __restrict__ bias, float* __restrict__ hout, int Nn) {
    const int lane = threadIdx.x & 63;
    const int n = (int)((blockIdx.x * 256u + threadIdx.x) >> 6);
    if (n >= Nn) return;

    const int dn = __builtin_amdgcn_readfirstlane(deg[n]);
    v4f bias4 = ((const v4f*)bias)[lane & 15];
    if (dn == 0) {
        if (lane < 16) {
            v4f o = {fmaxf(bias4.x, 0.f), fmaxf(bias4.y, 0.f),
                     fmaxf(bias4.z, 0.f), fmaxf(bias4.w, 0.f)};
            ((v4f*)hout)[(size_t)n * 16 + lane] = o;
        }
        return;
    }
    const int s0 = __builtin_amdgcn_readfirstlane(start[n]);
    const float* rf = (const float*)rec + (size_t)s0 * 20;  // uniform base
    const int* sI = sidx + s0;                              // uniform base

    // wave-invariant operands
    float4 attv = ((const float4*)att)[lane];
    float at0 = attv.x * LN2_INV, at1 = attv.y * LN2_INV;
    float at2 = attv.z * LN2_INV, at3 = attv.w * LN2_INV;
    v4f xrv = xr4p[(size_t)n * 64 + lane];
    // We, k-interleaved per dim: weI_d[p] = {We[2p][d], We[2p+1][d]}
    v2f weI0[10], weI1[10], weI2[10], weI3[10];
#pragma unroll
    for (int p = 0; p < 10; ++p) {
        float4 w0 = We4[(2 * p) * 64 + lane];
        float4 w1 = We4[(2 * p + 1) * 64 + lane];
        weI0[p].x = w0.x; weI0[p].y = w1.x;
        weI1[p].x = w0.y; weI1[p].y = w1.y;
        weI2[p].x = w0.z; weI2[p].y = w1.z;
        weI3[p].x = w0.w; weI3[p].y = w1.w;
    }
    const int bperm = ((lane & 48) | 15) << 2;

    v2f acc01 = {0.f, 0.f}, acc23 = {0.f, 0.f};
    float l = 0.f;

    // prologue: sk blocks 0,1; srcs 0..5; gathers 0..3; src chain at 4,5.
    float skA[20], skB[20];
    LOAD_BLOCK(skA, 0);
    LOAD_BLOCK(skB, 1);
    int e0 = sI[0], e1 = sI[1], e2 = sI[2], e3 = sI[3];
    int srcA = sI[4], srcB = sI[5];
    v4f xlA  = xl4p[(size_t)(unsigned)e0 * 64 + lane];
    v4f xlB  = xl4p[(size_t)(unsigned)e1 * 64 + lane];
    v4f xlA1 = xl4p[(size_t)(unsigned)e2 * 64 + lane];
    v4f xlB1 = xl4p[(size_t)(unsigned)e3 * 64 + lane];

    const int nfull = dn >> 1;
#pragma unroll 2
    for (int t = 0; t < nfull; ++t) {
        // phase A: edge 2t; issue gather for 2t+4; load src 2t+6; sk 2t+2
        v4f xlA2 = xl4p[(size_t)(unsigned)srcA * 64 + lane];
        PIN_V(xlA2);
        srcA = sI[2 * t + 6];
        PIN_S(srcA);
        COMPUTE_EDGE(skA, xlA);
        LOAD_BLOCK(skA, 2 * t + 2);
        xlA = xlA1; xlA1 = xlA2;
        // phase B: edge 2t+1; gather 2t+5; src 2t+7; sk 2t+3
        v4f xlB2 = xl4p[(size_t)(unsigned)srcB * 64 + lane];
        PIN_V(xlB2);
        srcB = sI[2 * t + 7];
        PIN_S(srcB);
        COMPUTE_EDGE(skB, xlB);
        LOAD_BLOCK(skB, 2 * t + 3);
        xlB = xlB1; xlB1 = xlB2;
    }
    if (dn & 1) COMPUTE_EDGE(skA, xlA);

    // epilogue: res = relu(bias + 0.25 * sum_h acc_h / l_h)
    float inv = 0.25f / l;
    v4f r = {acc01.x * inv, acc01.y * inv, acc23.x * inv, acc23.y * inv};
    r.x += __shfl_xor(r.x, 16, 64); r.x += __shfl_xor(r.x, 32, 64);
    r.y += __shfl_xor(r.y, 16, 64); r.y += __shfl_xor(r.y, 32, 64);
    r.z += __shfl_xor(r.z, 16, 64); r.z += __shfl_xor(r.z, 32, 64);
    r.w += __shfl_xor(r.w, 16, 64); r.w += __shfl_xor(r.w, 32, 64);
    if (lane < 16) {
        v4f o = {fmaxf(r.x + bias4.x, 0.f), fmaxf(r.y + bias4.y, 0.f),
                 fmaxf(r.z + bias4.z, 0.f), fmaxf(r.w + bias4.w, 0.f)};
        ((v4f*)hout)[(size_t)n * 16 + lane] = o;
    }
}

// ---------------------------------------------------------------------------
extern "C" void kernel_launch(void* const* d_in, const int* in_sizes, int n_in,
                              void* d_out, int out_size, void* d_ws, size_t ws_size,
                              hipStream_t stream) {
    const float* x     = (const float*)d_in[0];
    const float* eattr = (const float*)d_in[1];
    const int*   eidx  = (const int*)d_in[2];
    const float* fW    = (const float*)d_in[3];
    const float* fb    = (const float*)d_in[4];
    const float* feW   = (const float*)d_in[5];
    const float* feb   = (const float*)d_in[6];
    const float* Wl    = (const float*)d_in[7];
    const float* bl    = (const float*)d_in[8];
    const float* Wr    = (const float*)d_in[9];
    const float* br    = (const float*)d_in[10];
    const float* We    = (const float*)d_in[11];
    const float* att   = (const float*)d_in[12];
    const float* bias  = (const float*)d_in[13];
    float* out = (float*)d_out;

    const int N = in_sizes[0] / 128;   // 50000
    const int E = in_sizes[1] / 2;     // 800000
    const int* srcArr = eidx;
    const int* dstArr = eidx + E;

    char* p = (char*)d_ws;
    auto alloc = [&](size_t bytes) -> char* {
        char* r = p;
        p += (bytes + 255) & ~(size_t)255;
        return r;
    };
    float* hA   = (float*)alloc((size_t)N * 64 * 4);
    float* hB   = (float*)alloc((size_t)N * 64 * 4);
    float* xl   = (float*)alloc((size_t)N * 256 * 4);
    float* xr   = (float*)alloc((size_t)N * 256 * 4);
    int* deg    = (int*)alloc((size_t)N * 4);
    int* start  = (int*)alloc((size_t)N * 4);
    int* cursor = (int*)alloc((size_t)N * 4);
    int* counter = (int*)alloc(256);
    int* rec    = (int*)alloc((size_t)(E + 8) * 20 * 4);
    int* sidx   = (int*)alloc((size_t)(E + 8) * 4);

    k_h0<<<N / 8, 256, 0, stream>>>(x, fW, fb, hA);
    k_zero<<<(N + 255) / 256, 256, 0, stream>>>(deg, counter, rec, sidx, N, E);
    k_count<<<(E + 255) / 256, 256, 0, stream>>>(dstArr, deg, E);
    k_alloc<<<(N + 255) / 256, 256, 0, stream>>>(deg, counter, start, cursor, N);
    k_fill<<<(E + 255) / 256, 256, 0, stream>>>(dstArr, srcArr, eattr, feW, feb,
                                                cursor, rec, sidx, E);

    const float* hin = hA;
    for (int layer = 0; layer < 3; ++layer) {
        float* hout = (layer == 2) ? out : ((layer == 0) ? hB : hA);
        k_xlxr<<<N / 16, 256, 0, stream>>>(hin, Wl, Wr, bl, br, xl, xr);
        k_edge<<<(N * 64) / 256, 256, 0, stream>>>(
            (const v4f*)xl, (const v4f*)xr, att, (const float4*)We,
            rec, sidx, start, deg, bias, hout, N);
        hin = hout;
    }
}

// Round 7
// 920.936 us; speedup vs baseline: 1.3772x; 1.0354x over previous
//
#include <hip/hip_runtime.h>
#include <math.h>

typedef float v2f __attribute__((ext_vector_type(2)));

#define LN2_INV 1.4426950408889634f

__device__ __forceinline__ float fexp2(float x) {
#if __has_builtin(__builtin_amdgcn_exp2f)
    return __builtin_amdgcn_exp2f(x);
#else
    return exp2f(x);
#endif
}

__device__ __forceinline__ int rdlane_i(int v, int k) {
    return __builtin_amdgcn_readlane(v, k);
}

// packed f32 VOP3P (assemble+numerics proven on gfx950 in rounds 4-6).
// Exactly one scalar (SGPR-pair) source per instruction.
__device__ __forceinline__ v2f pk_fma(v2f a, v2f b, v2f c) {
    asm("v_pk_fma_f32 %0, %1, %2, %0" : "+v"(c) : "v"(a), "v"(b));
    return c;
}
__device__ __forceinline__ v2f pk_fma_s(v2f a_s, v2f b, v2f c) {
    asm("v_pk_fma_f32 %0, %1, %2, %0" : "+v"(c) : "s"(a_s), "v"(b));
    return c;
}
__device__ __forceinline__ v2f pk_mul_s(v2f a_s, v2f b) {
    v2f d;
    asm("v_pk_mul_f32 %0, %1, %2" : "=v"(d) : "s"(a_s), "v"(b));
    return d;
}

// v += dpp_shifted(v) within 16-lane rows; shifted-in lanes contribute 0.
#define DPP_ROW_ADD(V, CTRL) \
    V += __int_as_float(__builtin_amdgcn_update_dpp(0, __float_as_int(V), CTRL, 0xf, 0xf, true));

// ---------------------------------------------------------------------------
// k_h0: h0 = relu(x @ f_W + f_b), x [N,128], f_W [128,64]. 8 nodes/block.
// ---------------------------------------------------------------------------
__global__ __launch_bounds__(256) void k_h0(const float* __restrict__ x,
                                            const float* __restrict__ fW,
                                            const float* __restrict__ fb,
                                            float* __restrict__ h0) {
    __shared__ __align__(16) float xs[8 * 128];
    int t = threadIdx.x;
    int base = blockIdx.x * 8;
#pragma unroll
    for (int r = 0; r < 4; ++r) { int j = r * 256 + t; xs[j] = x[base * 128 + j]; }
    __syncthreads();
    int c = t & 63, half = t >> 6;
    float acc0 = fb[c], acc1 = fb[c];
    int m0 = half, m1 = half + 4;
#pragma unroll 8
    for (int k0 = 0; k0 < 128; k0 += 4) {
        float4 a = *(const float4*)&xs[m0 * 128 + k0];
        float4 b = *(const float4*)&xs[m1 * 128 + k0];
        float w0 = fW[(k0 + 0) * 64 + c], w1 = fW[(k0 + 1) * 64 + c];
        float w2 = fW[(k0 + 2) * 64 + c], w3 = fW[(k0 + 3) * 64 + c];
        acc0 = fmaf(a.x, w0, fmaf(a.y, w1, fmaf(a.z, w2, fmaf(a.w, w3, acc0))));
        acc1 = fmaf(b.x, w0, fmaf(b.y, w1, fmaf(b.z, w2, fmaf(b.w, w3, acc1))));
    }
    h0[(base + m0) * 64 + c] = fmaxf(acc0, 0.f);
    h0[(base + m1) * 64 + c] = fmaxf(acc1, 0.f);
}

// ---------------------------------------------------------------------------
// k_xlxr: xl = h@Wl + bl, xr = h@Wr + br, natural [N][256] layout (h*64+d).
// ---------------------------------------------------------------------------
__global__ __launch_bounds__(256) void k_xlxr(const float* __restrict__ h,
                                              const float* __restrict__ Wl,
                                              const float* __restrict__ Wr,
                                              const float* __restrict__ bl,
                                              const float* __restrict__ br,
                                              float* __restrict__ xl,
                                              float* __restrict__ xr) {
    __shared__ __align__(16) float hs[16 * 64];
    int t = threadIdx.x;
    int base = blockIdx.x * 16;
#pragma unroll
    for (int r = 0; r < 4; ++r) hs[r * 256 + t] = h[base * 64 + r * 256 + t];
    __syncthreads();
    float bL = bl[t], bR = br[t];
    float accl[16], accr[16];
#pragma unroll
    for (int m = 0; m < 16; ++m) { accl[m] = bL; accr[m] = bR; }
#pragma unroll 4
    for (int k0 = 0; k0 < 64; k0 += 4) {
        float wl[4], wr[4];
#pragma unroll
        for (int q = 0; q < 4; ++q) {
            wl[q] = Wl[(k0 + q) * 256 + t];
            wr[q] = Wr[(k0 + q) * 256 + t];
        }
#pragma unroll
        for (int m = 0; m < 16; ++m) {
            float4 hv = *(const float4*)&hs[m * 64 + k0];
            accl[m] = fmaf(hv.x, wl[0], fmaf(hv.y, wl[1], fmaf(hv.z, wl[2], fmaf(hv.w, wl[3], accl[m]))));
            accr[m] = fmaf(hv.x, wr[0], fmaf(hv.y, wr[1], fmaf(hv.z, wr[2], fmaf(hv.w, wr[3], accr[m]))));
        }
    }
#pragma unroll
    for (int m = 0; m < 16; ++m) {
        xl[(base + m) * 256 + t] = accl[m];
        xr[(base + m) * 256 + t] = accr[m];
    }
}

// ---------------------------------------------------------------------------
// CSR build. rec record (stride 24 ints): [0..19] = relu edge-MLP s_k,
// [20] = src node, [21..23] pad. Written at the CSR position directly.
// (Stride-24 + src-in-record is the R1 layout: lowest HBM fetch, 440 MB.)
// ---------------------------------------------------------------------------
__global__ void k_zero(int* __restrict__ deg, int* __restrict__ counter, int Nn) {
    int i = blockIdx.x * 256 + threadIdx.x;
    if (i < Nn) deg[i] = 0;
    if (i == 0) *counter = 0;
}

__global__ void k_count(const int* __restrict__ dstArr, int* __restrict__ deg, int Ee) {
    int e = blockIdx.x * 256 + threadIdx.x;
    if (e < Ee) atomicAdd(&deg[dstArr[e]], 1);
}

__global__ void k_alloc(const int* __restrict__ deg, int* __restrict__ counter,
                        int* __restrict__ start, int* __restrict__ cursor, int Nn) {
    int n = blockIdx.x * 256 + threadIdx.x;
    if (n < Nn) {
        int d = deg[n];
        int b = atomicAdd(counter, d);
        start[n] = b;
        cursor[n] = b;
    }
}

__global__ void k_fill(const int* __restrict__ dstArr, const int* __restrict__ srcArr,
                       const float* __restrict__ eattr, const float* __restrict__ feW,
                       const float* __restrict__ feb, int* __restrict__ cursor,
                       int* __restrict__ rec, int Ee) {
    int e = blockIdx.x * 256 + threadIdx.x;
    if (e >= Ee) return;
    float a0 = eattr[2 * e], a1 = eattr[2 * e + 1];
    int p = atomicAdd(&cursor[dstArr[e]], 1);
    float* r = (float*)(rec + (size_t)p * 24);
    float s[20];
#pragma unroll
    for (int k = 0; k < 20; ++k)
        s[k] = fmaxf(fmaf(a0, feW[k], fmaf(a1, feW[20 + k], feb[k])), 0.f);
#pragma unroll
    for (int j = 0; j < 5; ++j)
        ((float4*)r)[j] = make_float4(s[4 * j], s[4 * j + 1], s[4 * j + 2], s[4 * j + 3]);
    ((int*)r)[20] = srcArr[e];
}

// ---------------------------------------------------------------------------
// k_edge: R1 skeleton (one wave per dst node; record read as 1 dword/lane,
// broadcast via readlane; records 3 ahead, xl gathers 2 ahead; stride-24)
// + pk_fma matvec: weI_d[p] = {We[2p][d], We[2p+1][d]} consumed by
// v_pk_fma_f32 with the wave-uniform SGPR pair {s_2p, s_2p+1} built from two
// v_readlane. 80 scalar FMA -> 40 pk_fma; everything else is R1 verbatim.
// ---------------------------------------------------------------------------
__global__ __launch_bounds__(256, 3) void k_edge(
    const float4* __restrict__ xl4p, const float4* __restrict__ xr4p,
    const float* __restrict__ att, const float4* __restrict__ We4,
    const int* __restrict__ rec, const int* __restrict__ start,
    const int* __restrict__ deg, const float* __restrict__ bias,
    float* __restrict__ hout, int Nn) {
    const int lane = threadIdx.x & 63;
    const int n = (int)((blockIdx.x * 256u + threadIdx.x) >> 6);
    if (n >= Nn) return;

    const int dn = __builtin_amdgcn_readfirstlane(deg[n]);
    float4 bias4 = ((const float4*)bias)[lane & 15];
    if (dn == 0) {
        if (lane < 16) {
            float4 o = make_float4(fmaxf(bias4.x, 0.f), fmaxf(bias4.y, 0.f),
                                   fmaxf(bias4.z, 0.f), fmaxf(bias4.w, 0.f));
            ((float4*)hout)[(size_t)n * 16 + lane] = o;
        }
        return;
    }
    const int s0 = __builtin_amdgcn_readfirstlane(start[n]);
    const int* rb = rec + (size_t)s0 * 24 + (lane & 31);

    // wave-invariant operands
    float4 attv = ((const float4*)att)[lane];
    float at0 = attv.x * LN2_INV, at1 = attv.y * LN2_INV;
    float at2 = attv.z * LN2_INV, at3 = attv.w * LN2_INV;
    float4 xrv = xr4p[(size_t)n * 64 + lane];
    // We, k-interleaved per dim: weI_d[p] = {We[2p][d], We[2p+1][d]}
    v2f weI0[10], weI1[10], weI2[10], weI3[10];
#pragma unroll
    for (int p = 0; p < 10; ++p) {
        float4 w0 = We4[(2 * p) * 64 + lane];
        float4 w1 = We4[(2 * p + 1) * 64 + lane];
        weI0[p].x = w0.x; weI0[p].y = w1.x;
        weI1[p].x = w0.y; weI1[p].y = w1.y;
        weI2[p].x = w0.z; weI2[p].y = w1.z;
        weI3[p].x = w0.w; weI3[p].y = w1.w;
    }
    const int bperm = ((lane & 48) | 15) << 2;

    v2f acc01 = {0.f, 0.f}, acc23 = {0.f, 0.f};
    float l = 0.f;

    // prologue: records for edges 0,1,2; xl gathers for edges 0,1
    int i1 = dn > 1 ? 1 : 0;
    int i2p = dn > 2 ? 2 : (dn - 1);
    int rv0 = rb[0];
    int rv1 = rb[(size_t)i1 * 24];
    int rv2 = rb[(size_t)i2p * 24];
    int src0 = rdlane_i(rv0, 20);
    float4 xl0 = xl4p[(unsigned)(src0 * 64 + lane)];
    int src1 = rdlane_i(rv1, 20);
    float4 xl1 = xl4p[(unsigned)(src1 * 64 + lane)];

    for (int i = 0; i < dn; ++i) {
        // prefetch: record i+3, xl gather i+2 (uses rv2, loaded last iter)
        int i3 = (i + 3 < dn) ? (i + 3) : (dn - 1);
        int rvN = rb[(size_t)i3 * 24];
        int src2 = rdlane_i(rv2, 20);
        float4 xl2 = xl4p[(unsigned)(src2 * 64 + lane)];

        // ee matvec: 10 SGPR pairs {s_2p, s_2p+1} x 4 dim-groups of pk_fma
        v2f a0, a1, a2, a3;
        {
            v2f sp;
            sp.x = __int_as_float(rdlane_i(rv0, 0));
            sp.y = __int_as_float(rdlane_i(rv0, 1));
            a0 = pk_mul_s(sp, weI0[0]);
            a1 = pk_mul_s(sp, weI1[0]);
            a2 = pk_mul_s(sp, weI2[0]);
            a3 = pk_mul_s(sp, weI3[0]);
        }
#pragma unroll
        for (int p = 1; p < 10; ++p) {
            v2f sp;
            sp.x = __int_as_float(rdlane_i(rv0, 2 * p));
            sp.y = __int_as_float(rdlane_i(rv0, 2 * p + 1));
            a0 = pk_fma_s(sp, weI0[p], a0);
            a1 = pk_fma_s(sp, weI1[p], a1);
            a2 = pk_fma_s(sp, weI2[p], a2);
            a3 = pk_fma_s(sp, weI3[p], a3);
        }
        float v0 = (xl0.x + xrv.x) + (a0.x + a0.y);
        float v1 = (xl0.y + xrv.y) + (a1.x + a1.y);
        float v2 = (xl0.z + xrv.z) + (a2.x + a2.y);
        float v3 = (xl0.w + xrv.w) + (a3.x + a3.y);
        float m0 = fmaxf(v0, 0.2f * v0);
        float m1 = fmaxf(v1, 0.2f * v1);
        float m2 = fmaxf(v2, 0.2f * v2);
        float m3 = fmaxf(v3, 0.2f * v3);
        float ps = fmaf(at0, m0, fmaf(at1, m1, fmaf(at2, m2, at3 * m3)));
        DPP_ROW_ADD(ps, 0x111)
        DPP_ROW_ADD(ps, 0x112)
        DPP_ROW_ADD(ps, 0x114)
        DPP_ROW_ADD(ps, 0x118)
        float sc = __int_as_float(
            __builtin_amdgcn_ds_bpermute(bperm, __float_as_int(ps)));
        float w_ = fexp2(sc);
        l += w_;
        v2f w2 = {w_, w_};
        v2f xl01 = {xl0.x, xl0.y}, xl23 = {xl0.z, xl0.w};
        acc01 = pk_fma(w2, xl01, acc01);
        acc23 = pk_fma(w2, xl23, acc23);

        rv0 = rv1; rv1 = rv2; rv2 = rvN;
        xl0 = xl1; xl1 = xl2;
    }

    // epilogue: res = relu(bias + 0.25 * sum_h acc_h / l_h)
    float inv = 0.25f / l;
    float4 r = make_float4(acc01.x * inv, acc01.y * inv, acc23.x * inv, acc23.y * inv);
    r.x += __shfl_xor(r.x, 16, 64); r.x += __shfl_xor(r.x, 32, 64);
    r.y += __shfl_xor(r.y, 16, 64); r.y += __shfl_xor(r.y, 32, 64);
    r.z += __shfl_xor(r.z, 16, 64); r.z += __shfl_xor(r.z, 32, 64);
    r.w += __shfl_xor(r.w, 16, 64); r.w += __shfl_xor(r.w, 32, 64);
    if (lane < 16) {
        float4 o = make_float4(fmaxf(r.x + bias4.x, 0.f), fmaxf(r.y + bias4.y, 0.f),
                               fmaxf(r.z + bias4.z, 0.f), fmaxf(r.w + bias4.w, 0.f));
        ((float4*)hout)[(size_t)n * 16 + lane] = o;
    }
}

// ---------------------------------------------------------------------------
extern "C" void kernel_launch(void* const* d_in, const int* in_sizes, int n_in,
                              void* d_out, int out_size, void* d_ws, size_t ws_size,
                              hipStream_t stream) {
    const float* x     = (const float*)d_in[0];
    const float* eattr = (const float*)d_in[1];
    const int*   eidx  = (const int*)d_in[2];
    const float* fW    = (const float*)d_in[3];
    const float* fb    = (const float*)d_in[4];
    const float* feW   = (const float*)d_in[5];
    const float* feb   = (const float*)d_in[6];
    const float* Wl    = (const float*)d_in[7];
    const float* bl    = (const float*)d_in[8];
    const float* Wr    = (const float*)d_in[9];
    const float* br    = (const float*)d_in[10];
    const float* We    = (const float*)d_in[11];
    const float* att   = (const float*)d_in[12];
    const float* bias  = (const float*)d_in[13];
    float* out = (float*)d_out;

    const int N = in_sizes[0] / 128;   // 50000
    const int E = in_sizes[1] / 2;     // 800000
    const int* srcArr = eidx;
    const int* dstArr = eidx + E;

    char* p = (char*)d_ws;
    auto alloc = [&](size_t bytes) -> char* {
        char* r = p;
        p += (bytes + 255) & ~(size_t)255;
        return r;
    };
    float* hA   = (float*)alloc((size_t)N * 64 * 4);
    float* hB   = (float*)alloc((size_t)N * 64 * 4);
    float* xl   = (float*)alloc((size_t)N * 256 * 4);
    float* xr   = (float*)alloc((size_t)N * 256 * 4);
    int* deg    = (int*)alloc((size_t)N * 4);
    int* start  = (int*)alloc((size_t)N * 4);
    int* cursor = (int*)alloc((size_t)N * 4);
    int* counter = (int*)alloc(256);
    int* rec    = (int*)alloc((size_t)E * 24 * 4);

    k_h0<<<N / 8, 256, 0, stream>>>(x, fW, fb, hA);
    k_zero<<<(N + 255) / 256, 256, 0, stream>>>(deg, counter, N);
    k_count<<<(E + 255) / 256, 256, 0, stream>>>(dstArr, deg, E);
    k_alloc<<<(N + 255) / 256, 256, 0, stream>>>(deg, counter, start, cursor, N);
    k_fill<<<(E + 255) / 256, 256, 0, stream>>>(dstArr, srcArr, eattr, feW, feb,
                                                cursor, rec, E);

    const float* hin = hA;
    for (int layer = 0; layer < 3; ++layer) {
        float* hout = (layer == 2) ? out : ((layer == 0) ? hB : hA);
        k_xlxr<<<N / 16, 256, 0, stream>>>(hin, Wl, Wr, bl, br, xl, xr);
        k_edge<<<(N * 64) / 256, 256, 0, stream>>>(
            (const float4*)xl, (const float4*)xr, att, (const float4*)We,
            rec, start, deg, bias, hout, N);
        hin = hout;
    }
}